// Round 5
// baseline (1002.383 us; speedup 1.0000x reference)
//
#include <hip/hip_runtime.h>
#include <math.h>

#define N_NODES 50000
#define N_EDGES 800000
#define DIN 128
#define DH 256
#define DOUT 64
#define NLAYERS 4

typedef unsigned short u16;
typedef __attribute__((ext_vector_type(8))) _Float16 half8;
typedef __attribute__((ext_vector_type(4))) float f32x4;
typedef __attribute__((ext_vector_type(2))) int i32x2;
typedef __attribute__((ext_vector_type(4))) unsigned short u16x4;

__device__ inline u16 f2h(float f) {
  _Float16 h = (_Float16)f;
  return *(u16*)&h;
}
__device__ inline float h2f(u16 u) {
  _Float16 h = *(_Float16*)&u;
  return (float)h;
}
// stored index j -> true feature index (perm: true c -> (c%16)*4 + c/16 per 64-seg)
__device__ inline int invp(int j) {
  int s = j >> 6, t = j & 63;
  return s * 64 + (t & 3) * 16 + (t >> 2);
}

#define GLD16(gp, lp)                                                        \
  __builtin_amdgcn_global_load_lds(                                          \
      (const __attribute__((address_space(1))) void*)(const void*)(gp),      \
      (__attribute__((address_space(3))) void*)(void*)(lp), 16, 0, 0)

// ---------------- preprocessing ----------------

// scan1 + dinv fused
__global__ void k_scan1(const int* __restrict__ cnt, int* __restrict__ rowptr,
                        int* __restrict__ bsum, float* __restrict__ dinv, int n) {
  __shared__ int sm[256];
  int i = blockIdx.x * 256 + threadIdx.x;
  int v = (i < n) ? cnt[i] : 0;
  if (i < n) dinv[i] = rsqrtf((float)v + 1.0f);  // +1 = self-loop
  sm[threadIdx.x] = v;
  __syncthreads();
  for (int off = 1; off < 256; off <<= 1) {
    int t = (threadIdx.x >= off) ? sm[threadIdx.x - off] : 0;
    __syncthreads();
    sm[threadIdx.x] += t;
    __syncthreads();
  }
  if (i < n) rowptr[i + 1] = sm[threadIdx.x];
  if (threadIdx.x == 255) bsum[blockIdx.x] = sm[255];
}

__global__ void k_scan2(int* bsum, int nb) {
  __shared__ int sm[256];
  int v = (threadIdx.x < nb) ? bsum[threadIdx.x] : 0;
  sm[threadIdx.x] = v;
  __syncthreads();
  for (int off = 1; off < 256; off <<= 1) {
    int t = (threadIdx.x >= off) ? sm[threadIdx.x - off] : 0;
    __syncthreads();
    sm[threadIdx.x] += t;
    __syncthreads();
  }
  if (threadIdx.x < nb) bsum[threadIdx.x] = sm[threadIdx.x] - v;
}

// scan3 + cursor init fused
__global__ void k_scan3(int* __restrict__ rowptr, const int* __restrict__ bsum,
                        int* __restrict__ cursor, int n) {
  int i = blockIdx.x * 256 + threadIdx.x;
  if (i < n) {
    int v = rowptr[i + 1] + bsum[blockIdx.x];
    rowptr[i + 1] = v;
    if (i + 1 < n) cursor[i + 1] = v;
  }
  if (blockIdx.x == 0 && threadIdx.x == 0) {
    rowptr[0] = 0;
    cursor[0] = 0;
  }
}

__global__ void k_fill(const int* __restrict__ src, const int* __restrict__ dst,
                       const float* __restrict__ dinv,
                       int* __restrict__ cursor, int2* __restrict__ csr, int e) {
  int i = blockIdx.x * blockDim.x + threadIdx.x;
  if (i < e) {
    int d = dst[i], s = src[i];
    int pos = atomicAdd(&cursor[d], 1);
    csr[pos] = make_int2(s, __float_as_int(dinv[s] * dinv[d]));
  }
}

// ---------------- convert: x, weights (k-inverse-perm), biases (perm), + count ----
#define X_Q (N_NODES * DIN / 4)        // 1,600,000 float4 groups
#define W_EMB_SZ (DIN * DH)            // 32768 (plain: emb k-dim is unpermuted x)
#define W_CONV_SZ (DH * DH)            // 65536
#define W_OUT_SZ (3 * DH * DOUT)       // 49152
#define W_TOT (W_EMB_SZ + 4 * W_CONV_SZ + W_OUT_SZ)
#define B_TOT (DH + 4 * DH)            // permuted b_emb + b_conv

__global__ void k_convert(const float* __restrict__ x, u16* __restrict__ x_f16,
                          const float* __restrict__ W_emb, const float* __restrict__ W_conv,
                          const float* __restrict__ W_out,
                          const float* __restrict__ b_emb, const float* __restrict__ b_conv,
                          u16* __restrict__ Bt_emb, u16* __restrict__ Bt_conv,
                          u16* __restrict__ Bt_out,
                          float* __restrict__ bEmbP, float* __restrict__ bConvP,
                          const int* __restrict__ edst, int* __restrict__ cnt) {
  int i = blockIdx.x * 256 + threadIdx.x;
  if (i < X_Q) {
    float4 v = ((const float4*)x)[i];
    ushort4 o;
    o.x = f2h(v.x); o.y = f2h(v.y); o.z = f2h(v.z); o.w = f2h(v.w);
    ((ushort4*)x_f16)[i] = o;
    return;
  }
  int t = i - X_Q;
  if (t < W_EMB_SZ) {
    int n = t >> 7, k = t & (DIN - 1);           // Bt_emb[n][k], k plain
    Bt_emb[t] = f2h(W_emb[k * DH + n]);
  } else if (t < W_EMB_SZ + 4 * W_CONV_SZ) {
    int j = t - W_EMB_SZ;
    int l = j >> 16, jj = j & (W_CONV_SZ - 1);
    int n = jj >> 8, k2 = jj & (DH - 1);         // Bt_conv[n][k2], k2 = perm space
    Bt_conv[j] = f2h(W_conv[l * W_CONV_SZ + invp(k2) * DH + n]);
  } else if (t < W_TOT) {
    int j = t - W_EMB_SZ - 4 * W_CONV_SZ;
    int n = j / (3 * DH), kp = j % (3 * DH);     // Bt_out[n][kp]: 0..255 hi,256.. lo,512.. hi
    int s0 = kp >> 8, k2 = kp & (DH - 1);
    float wv = W_out[invp(k2) * DOUT + n];
    u16 hiv = f2h(wv);
    u16 v = hiv;
    if (s0 == 1) v = f2h(wv - h2f(hiv));
    Bt_out[j] = v;
  } else {
    int t2 = t - W_TOT;
    if (t2 < B_TOT) {
      if (t2 < DH) bEmbP[t2] = b_emb[invp(t2)];
      else {
        int j = t2 - DH, l = j >> 8, jj = j & (DH - 1);
        bConvP[j] = b_conv[l * DH + invp(jj)];
      }
    } else {
      int t3 = t2 - B_TOT;
      if (t3 < N_EDGES) atomicAdd(&cnt[edst[t3]], 1);
    }
  }
}

// ---------------- f16 MFMA GEMM: A via LDS, B direct from L2 ----------------
// C[M][N] = A[M][K']·B2[K'][N]; A = (Ahi, Alo) f16 [M][K] (feature order = caller's).
// NSPLIT=1: K'=K. NSPLIT=3: K'=3K, (Ahi·Bhi)+(Ahi·Blo)+(Alo·Bhi); Bt segments
// [0,K) hi, [K,2K) lo, [2K,3K) hi. Bt = B2^T [N][K'] f16 (L2-resident weight).
// BM=128, BK=64, 4 waves, wave tile 64 x (BN/2). A staged via GLD16 in
// fragment-order LDS (conflict-free); B fragments loaded straight to VGPRs.
// EPI 0: Cf fp32 + bias, TRUE col order (scalar stores).
// EPI 1: Cb f16 + biasp, PERM col order (ushort4 stores), row-major [M][N].
// EPI 2: Cb f16 + biasp, PERM col order, SLICE-MAJOR [8][M][32] (32-feature
//        slices contiguous per slice -> XCD-L2-resident gather target).
template <int BN, int NSPLIT, int EPI>
__global__ __launch_bounds__(256) void k_gemm_mfma(
    const u16* __restrict__ Ahi, const u16* __restrict__ Alo,
    const u16* __restrict__ Bt, const float* __restrict__ bias,
    float* __restrict__ Cf, u16* __restrict__ Cb, int M, int K, int N) {
  constexpr int BM = 128, BK = 64;
  constexpr int WN = BN / 2;
  constexpr int NT = WN / 16;
  __shared__ u16 As[2 * 8 * 512];  // (kb, g<8, lane*8) : 16 KB
  const int tid = threadIdx.x;
  const int w = tid >> 6, lane = tid & 63;
  const int q = lane >> 4, r = lane & 15;
  const int wmg = (w >> 1) * 4;       // A group base for this wave
  const int wn = (w & 1) * WN;
  const int m0 = blockIdx.x * BM, n0 = blockIdx.y * BN;
  const int Kp = NSPLIT * K;
  const int srow = lane & 15;         // staging source row within group
  const int sk = (lane >> 4) * 8;     // staging source k offset

  f32x4 acc[4][NT];
#pragma unroll
  for (int t = 0; t < 4; t++)
#pragma unroll
    for (int u = 0; u < NT; u++) acc[t][u] = (f32x4){0.f, 0.f, 0.f, 0.f};

  for (int k0 = 0; k0 < Kp; k0 += BK) {
    const u16* Aptr;
    int ka;
    if (NSPLIT == 1) {
      Aptr = Ahi; ka = k0;
    } else {
      Aptr = (k0 < 2 * K) ? Ahi : Alo;
      ka = (k0 < K) ? k0 : ((k0 < 2 * K) ? (k0 - K) : (k0 - 2 * K));
    }
    // stage A: 16 slots over 4 waves x 4 issues
#pragma unroll
    for (int ii = 0; ii < 4; ii++) {
      int g = w * 2 + (ii & 1), kb = ii >> 1;
      int grow = m0 + g * 16 + srow;
      if (grow > M - 1) grow = M - 1;
      const u16* gp = Aptr + (size_t)grow * K + ka + kb * 32 + sk;
      GLD16(gp, &As[(kb * 8 + g) * 512] + (size_t)lane * 8);
    }
    __syncthreads();
#pragma unroll
    for (int kb = 0; kb < 2; kb++) {
      half8 af[4], bfr[NT];
#pragma unroll
      for (int u = 0; u < NT; u++)
        bfr[u] = *(const half8*)(Bt + (size_t)(n0 + wn + u * 16 + r) * Kp +
                                 k0 + kb * 32 + q * 8);
#pragma unroll
      for (int t = 0; t < 4; t++)
        af[t] = *(const half8*)&As[((kb * 8 + wmg + t) * 64 + lane) * 8];
#pragma unroll
      for (int t = 0; t < 4; t++)
#pragma unroll
        for (int u = 0; u < NT; u++)
          acc[t][u] = __builtin_amdgcn_mfma_f32_16x16x32_f16(af[t], bfr[u], acc[t][u], 0, 0, 0);
    }
    __syncthreads();
  }

  if (EPI >= 1) {
    // perm epilogue: lane holds true cols cb+u*16+r -> stored cb + r*4 + u
    int cb = n0 + wn;
    float4 bp = bias ? *(const float4*)(bias + cb + r * 4)
                     : make_float4(0.f, 0.f, 0.f, 0.f);
    int c = cb + r * 4;
    // EPI1: row-major offset = row*N + c. EPI2: slice-major [8][M][32]:
    // offset = (c>>5)*M*32 + row*32 + (c&31)   (ushort4 stays within slice)
    size_t sb2 = (size_t)(c >> 5) * ((size_t)M * 32) + (c & 31);
#pragma unroll
    for (int t = 0; t < 4; t++) {
#pragma unroll
      for (int rg = 0; rg < 4; rg++) {
        int row = m0 + (w >> 1) * 64 + t * 16 + q * 4 + rg;
        if (row < M) {
          ushort4 o;
          o.x = f2h(acc[t][0][rg] + bp.x);
          o.y = f2h(acc[t][1][rg] + bp.y);
          o.z = f2h(acc[t][2][rg] + bp.z);
          o.w = f2h(acc[t][3][rg] + bp.w);
          if (EPI == 1)
            *(ushort4*)(Cb + (size_t)row * N + c) = o;
          else
            *(ushort4*)(Cb + sb2 + (size_t)row * 32) = o;
        }
      }
    }
  } else {
    float bv[NT];
#pragma unroll
    for (int u = 0; u < NT; u++) bv[u] = bias ? bias[n0 + wn + u * 16 + r] : 0.f;
#pragma unroll
    for (int t = 0; t < 4; t++) {
#pragma unroll
      for (int rg = 0; rg < 4; rg++) {
        int row = m0 + (w >> 1) * 64 + t * 16 + q * 4 + rg;
        if (row < M) {
#pragma unroll
          for (int u = 0; u < NT; u++) {
            int col = n0 + wn + u * 16 + r;
            Cf[(size_t)row * N + col] = acc[t][u][rg] + bv[u];
          }
        }
      }
    }
  }
}

// ---------------- aggregation v5: dynamic-XCD feature-sharded (f16; perm) ----
// h[i] = tanh(b + dinv[i]^2*tmp[i] + sum_e w_e*tmp[src_e]).
// tmph is SLICE-MAJOR [8][n][32]: slice s = contiguous 3.2 MB.
// Affinity is mapping-independent: block reads its REAL XCD id via
// s_getreg(HW_REG_XCC_ID) (HW-verified, learn_hip m09) and claims a chunk
// from per-slice atomic queue xcc first, stealing from others only when
// exhausted. grid == 8*nchunks => every (slice,chunk) claimed exactly once
// regardless of what XCC_ID returns (correctness never depends on it).
// csr loads nontemporal (no L2 allocate -> 6.4 MB/XCD stream can't evict the
// 3.2 MB resident slice); h stores nontemporal. Per-feature accumulation
// order (ascending j, 16-chunks + clamped-16 tail) identical to round 1/4.
__global__ __launch_bounds__(256) void k_aggregate(
    const u16* __restrict__ tmph,
    const int* __restrict__ rowptr, const int2* __restrict__ csr,
    const float* __restrict__ dinv, const float* __restrict__ bias,
    u16* __restrict__ hi, u16* __restrict__ lo,
    int* __restrict__ workq, int nchunks, int n) {
  __shared__ int sm[2];
  if (threadIdx.x == 0) {
    int xcc;
    asm volatile("s_getreg_b32 %0, hwreg(HW_REG_XCC_ID)" : "=s"(xcc));
    xcc &= 7;
    int sl = 0, got = 0;
#pragma unroll 1
    for (int t = 0; t < 8; t++) {
      int s2 = (xcc + t) & 7;
      int c = atomicAdd(&workq[s2], 1);
      if (c < nchunks) { sl = s2; got = c; break; }
    }
    sm[0] = sl; sm[1] = got;
  }
  __syncthreads();
  const int slice = sm[0];
  const int chunk = sm[1];
  const int lane = threadIdx.x & 63;
  const int wave = threadIdx.x >> 6;
  const int grp = lane >> 3, sub = lane & 7;
  const int i = chunk * 32 + wave * 8 + grp;
  if (i >= n) return;
  const int fo = slice * 32 + sub * 4;     // stored (perm) feature offset
  const u16x4* T = (const u16x4*)(tmph + (size_t)slice * ((size_t)N_NODES * 32));
  float w0 = dinv[i];
  w0 *= w0;
  float4 bv = *(const float4*)(bias + fo);
  u16x4 t0 = T[(size_t)i * 8 + sub];
  float ax = bv.x + w0 * h2f(t0[0]);
  float ay = bv.y + w0 * h2f(t0[1]);
  float az = bv.z + w0 * h2f(t0[2]);
  float aw = bv.w + w0 * h2f(t0[3]);
  int s = rowptr[i], e = rowptr[i + 1];
  int j = s;
  // main: 16-edge chunks = one csr->gather dependency round
  for (; j + 16 <= e; j += 16) {
    i32x2 c[16];
    u16x4 v[16];
#pragma unroll
    for (int u = 0; u < 16; u++)
      c[u] = __builtin_nontemporal_load((const i32x2*)(csr + j + u));
#pragma unroll
    for (int u = 0; u < 16; u++) v[u] = T[(size_t)c[u][0] * 8 + sub];
#pragma unroll
    for (int u = 0; u < 16; u++) {
      float f = __int_as_float(c[u][1]);
      ax += f * h2f(v[u][0]);
      ay += f * h2f(v[u][1]);
      az += f * h2f(v[u][2]);
      aw += f * h2f(v[u][3]);
    }
  }
  // tail: one clamped 16-chunk (<=15 real edges); padded slots add 0.0
  if (j < e) {
    i32x2 c[16];
    float f[16];
    u16x4 v[16];
#pragma unroll
    for (int u = 0; u < 16; u++) {
      int idx = j + u;
      int cl = idx < e ? idx : e - 1;
      c[u] = __builtin_nontemporal_load((const i32x2*)(csr + cl));
      f[u] = idx < e ? __int_as_float(c[u][1]) : 0.f;
    }
#pragma unroll
    for (int u = 0; u < 16; u++) v[u] = T[(size_t)c[u][0] * 8 + sub];
#pragma unroll
    for (int u = 0; u < 16; u++) {
      ax += f[u] * h2f(v[u][0]);
      ay += f[u] * h2f(v[u][1]);
      az += f[u] * h2f(v[u][2]);
      aw += f[u] * h2f(v[u][3]);
    }
  }
  float ox = tanhf(ax), oy = tanhf(ay), oz = tanhf(az), ow = tanhf(aw);
  size_t base = (size_t)i * DH + fo;   // h stays row-major for the GEMMs
  u16x4 hv;
  hv[0] = f2h(ox); hv[1] = f2h(oy); hv[2] = f2h(oz); hv[3] = f2h(ow);
  __builtin_nontemporal_store(hv, (u16x4*)(hi + base));
  if (lo) {
    u16x4 lv;
    lv[0] = f2h(ox - h2f(hv[0]));
    lv[1] = f2h(oy - h2f(hv[1]));
    lv[2] = f2h(oz - h2f(hv[2]));
    lv[3] = f2h(ow - h2f(hv[3]));
    __builtin_nontemporal_store(lv, (u16x4*)(lo + base));
  }
}

// ---------------- launch ----------------

extern "C" void kernel_launch(void* const* d_in, const int* in_sizes, int n_in,
                              void* d_out, int out_size, void* d_ws, size_t ws_size,
                              hipStream_t stream) {
  const float* x = (const float*)d_in[0];
  const int* eidx = (const int*)d_in[1];
  const int* esrc = eidx;
  const int* edst = eidx + N_EDGES;
  const float* W_emb = (const float*)d_in[2];
  const float* b_emb = (const float*)d_in[3];
  const float* W_conv = (const float*)d_in[4];
  const float* b_conv = (const float*)d_in[5];
  const float* W_out = (const float*)d_in[6];
  const float* b_out = (const float*)d_in[7];
  float* out = (float*)d_out;

  char* ws = (char*)d_ws;
  size_t off = 0;
  auto alloc = [&](size_t bytes) -> void* {
    void* p = ws + off;
    off += (bytes + 255) & ~(size_t)255;
    return p;
  };
  u16* tmph = (u16*)alloc((size_t)N_NODES * DH * 2);
  u16* h_hi = (u16*)alloc((size_t)N_NODES * DH * 2);
  u16* h_lo = (u16*)alloc((size_t)N_NODES * DH * 2);
  u16* x_f16 = h_lo;  // alias: x_f16 dead after emb GEMM; h_lo first written at layer-3 agg
  float* dinv = (float*)alloc((size_t)N_NODES * 4);
  int* cnt = (int*)alloc((size_t)N_NODES * 4);
  int* rowptr = (int*)alloc((size_t)(N_NODES + 1) * 4);
  int* cursor = (int*)alloc((size_t)N_NODES * 4);
  int* bsum = (int*)alloc((size_t)((N_NODES + 255) / 256) * 4);
  int2* csr = (int2*)alloc((size_t)N_EDGES * 8);
  u16* Bt_emb = (u16*)alloc((size_t)W_EMB_SZ * 2);
  u16* Bt_conv = (u16*)alloc((size_t)4 * W_CONV_SZ * 2);
  u16* Bt_out = (u16*)alloc((size_t)W_OUT_SZ * 2);
  float* bEmbP = (float*)alloc((size_t)DH * 4);
  float* bConvP = (float*)alloc((size_t)4 * DH * 4);
  int* workq = (int*)alloc((size_t)NLAYERS * 8 * 4);

  int nb = (N_NODES + 255) / 256;
  int eb = (N_EDGES + 255) / 256;

  hipMemsetAsync(cnt, 0, (size_t)N_NODES * 4, stream);
  hipMemsetAsync(workq, 0, (size_t)NLAYERS * 8 * 4, stream);
  {
    int tot = X_Q + W_TOT + B_TOT + N_EDGES;
    k_convert<<<(tot + 255) / 256, 256, 0, stream>>>(x, x_f16, W_emb, W_conv, W_out,
                                                     b_emb, b_conv, Bt_emb, Bt_conv,
                                                     Bt_out, bEmbP, bConvP, edst, cnt);
  }
  k_scan1<<<nb, 256, 0, stream>>>(cnt, rowptr, bsum, dinv, N_NODES);
  k_scan2<<<1, 256, 0, stream>>>(bsum, nb);
  k_scan3<<<nb, 256, 0, stream>>>(rowptr, bsum, cursor, N_NODES);
  k_fill<<<eb, 256, 0, stream>>>(esrc, edst, dinv, cursor, csr, N_EDGES);

  int mblocks = (N_NODES + 127) / 128;  // 391
  int nchunks = (N_NODES + 31) / 32;    // 1563
  int aggblocks = nchunks * 8;          // one block per (chunk, slice)

  // emb: h0 = x @ W_emb + b_emb  -> f16 h_hi (perm cols, row-major)
  {
    dim3 g(mblocks, DH / 128);
    k_gemm_mfma<128, 1, 1><<<g, 256, 0, stream>>>(x_f16, nullptr, Bt_emb, bEmbP,
                                                  nullptr, h_hi, N_NODES, DIN, DH);
  }
  // conv layers: GEMM writes tmph SLICE-MAJOR (EPI 2); layer 3 agg also emits
  // h_lo for the final split GEMM
  for (int l = 0; l < NLAYERS; l++) {
    dim3 g(mblocks, DH / 128);
    k_gemm_mfma<128, 1, 2><<<g, 256, 0, stream>>>(h_hi, nullptr,
                                                  Bt_conv + (size_t)l * W_CONV_SZ, nullptr,
                                                  nullptr, tmph, N_NODES, DH, DH);
    k_aggregate<<<aggblocks, 256, 0, stream>>>(tmph, rowptr, csr, dinv,
                                               bConvP + (size_t)l * DH,
                                               h_hi, (l == 3) ? h_lo : nullptr,
                                               workq + l * 8, nchunks, N_NODES);
  }
  // out = h4 @ W_out + b_out (split-3, fp32 out, TRUE col order)
  {
    dim3 g(mblocks, 1);
    k_gemm_mfma<64, 3, 0><<<g, 256, 0, stream>>>(h_hi, h_lo, Bt_out, b_out,
                                                 out, nullptr, N_NODES, DH, DOUT);
  }
}

// Round 8
// 983.231 us; speedup vs baseline: 1.0195x; 1.0195x over previous
//
#include <hip/hip_runtime.h>
#include <math.h>

#define N_NODES 50000
#define N_EDGES 800000
#define DIN 128
#define DH 256
#define DOUT 64
#define NLAYERS 4
#define AGG_CAP 1024  // LDS edge-buffer entries per pass (avg block load ~544)

typedef unsigned short u16;
typedef __attribute__((ext_vector_type(8))) _Float16 half8;
typedef __attribute__((ext_vector_type(4))) float f32x4;
typedef __attribute__((ext_vector_type(2))) int i32x2;
typedef __attribute__((ext_vector_type(4))) unsigned short u16x4;

__device__ inline u16 f2h(float f) {
  _Float16 h = (_Float16)f;
  return *(u16*)&h;
}
__device__ inline float h2f(u16 u) {
  _Float16 h = *(_Float16*)&u;
  return (float)h;
}
// stored index j -> true feature index (perm: true c -> (c%16)*4 + c/16 per 64-seg)
__device__ inline int invp(int j) {
  int s = j >> 6, t = j & 63;
  return s * 64 + (t & 3) * 16 + (t >> 2);
}

#define GLD16(gp, lp)                                                        \
  __builtin_amdgcn_global_load_lds(                                          \
      (const __attribute__((address_space(1))) void*)(const void*)(gp),      \
      (__attribute__((address_space(3))) void*)(void*)(lp), 16, 0, 0)

// ---------------- preprocessing ----------------

// scan1 + dinv fused
__global__ void k_scan1(const int* __restrict__ cnt, int* __restrict__ rowptr,
                        int* __restrict__ bsum, float* __restrict__ dinv, int n) {
  __shared__ int sm[256];
  int i = blockIdx.x * 256 + threadIdx.x;
  int v = (i < n) ? cnt[i] : 0;
  if (i < n) dinv[i] = rsqrtf((float)v + 1.0f);  // +1 = self-loop
  sm[threadIdx.x] = v;
  __syncthreads();
  for (int off = 1; off < 256; off <<= 1) {
    int t = (threadIdx.x >= off) ? sm[threadIdx.x - off] : 0;
    __syncthreads();
    sm[threadIdx.x] += t;
    __syncthreads();
  }
  if (i < n) rowptr[i + 1] = sm[threadIdx.x];
  if (threadIdx.x == 255) bsum[blockIdx.x] = sm[255];
}

__global__ void k_scan2(int* bsum, int nb) {
  __shared__ int sm[256];
  int v = (threadIdx.x < nb) ? bsum[threadIdx.x] : 0;
  sm[threadIdx.x] = v;
  __syncthreads();
  for (int off = 1; off < 256; off <<= 1) {
    int t = (threadIdx.x >= off) ? sm[threadIdx.x - off] : 0;
    __syncthreads();
    sm[threadIdx.x] += t;
    __syncthreads();
  }
  if (threadIdx.x < nb) bsum[threadIdx.x] = sm[threadIdx.x] - v;
}

// scan3 + cursor init fused
__global__ void k_scan3(int* __restrict__ rowptr, const int* __restrict__ bsum,
                        int* __restrict__ cursor, int n) {
  int i = blockIdx.x * 256 + threadIdx.x;
  if (i < n) {
    int v = rowptr[i + 1] + bsum[blockIdx.x];
    rowptr[i + 1] = v;
    if (i + 1 < n) cursor[i + 1] = v;
  }
  if (blockIdx.x == 0 && threadIdx.x == 0) {
    rowptr[0] = 0;
    cursor[0] = 0;
  }
}

__global__ void k_fill(const int* __restrict__ src, const int* __restrict__ dst,
                       const float* __restrict__ dinv,
                       int* __restrict__ cursor, int2* __restrict__ csr, int e) {
  int i = blockIdx.x * blockDim.x + threadIdx.x;
  if (i < e) {
    int d = dst[i], s = src[i];
    int pos = atomicAdd(&cursor[d], 1);
    csr[pos] = make_int2(s, __float_as_int(dinv[s] * dinv[d]));
  }
}

// ---------------- convert: x, weights (k-inverse-perm), biases (perm), + count ----
#define X_Q (N_NODES * DIN / 4)        // 1,600,000 float4 groups
#define W_EMB_SZ (DIN * DH)            // 32768 (plain: emb k-dim is unpermuted x)
#define W_CONV_SZ (DH * DH)            // 65536
#define W_OUT_SZ (3 * DH * DOUT)       // 49152
#define W_TOT (W_EMB_SZ + 4 * W_CONV_SZ + W_OUT_SZ)
#define B_TOT (DH + 4 * DH)            // permuted b_emb + b_conv

__global__ void k_convert(const float* __restrict__ x, u16* __restrict__ x_f16,
                          const float* __restrict__ W_emb, const float* __restrict__ W_conv,
                          const float* __restrict__ W_out,
                          const float* __restrict__ b_emb, const float* __restrict__ b_conv,
                          u16* __restrict__ Bt_emb, u16* __restrict__ Bt_conv,
                          u16* __restrict__ Bt_out,
                          float* __restrict__ bEmbP, float* __restrict__ bConvP,
                          const int* __restrict__ edst, int* __restrict__ cnt) {
  int i = blockIdx.x * 256 + threadIdx.x;
  if (i < X_Q) {
    float4 v = ((const float4*)x)[i];
    ushort4 o;
    o.x = f2h(v.x); o.y = f2h(v.y); o.z = f2h(v.z); o.w = f2h(v.w);
    ((ushort4*)x_f16)[i] = o;
    return;
  }
  int t = i - X_Q;
  if (t < W_EMB_SZ) {
    int n = t >> 7, k = t & (DIN - 1);           // Bt_emb[n][k], k plain
    Bt_emb[t] = f2h(W_emb[k * DH + n]);
  } else if (t < W_EMB_SZ + 4 * W_CONV_SZ) {
    int j = t - W_EMB_SZ;
    int l = j >> 16, jj = j & (W_CONV_SZ - 1);
    int n = jj >> 8, k2 = jj & (DH - 1);         // Bt_conv[n][k2], k2 = perm space
    Bt_conv[j] = f2h(W_conv[l * W_CONV_SZ + invp(k2) * DH + n]);
  } else if (t < W_TOT) {
    int j = t - W_EMB_SZ - 4 * W_CONV_SZ;
    int n = j / (3 * DH), kp = j % (3 * DH);     // Bt_out[n][kp]: 0..255 hi,256.. lo,512.. hi
    int s0 = kp >> 8, k2 = kp & (DH - 1);
    float wv = W_out[invp(k2) * DOUT + n];
    u16 hiv = f2h(wv);
    u16 v = hiv;
    if (s0 == 1) v = f2h(wv - h2f(hiv));
    Bt_out[j] = v;
  } else {
    int t2 = t - W_TOT;
    if (t2 < B_TOT) {
      if (t2 < DH) bEmbP[t2] = b_emb[invp(t2)];
      else {
        int j = t2 - DH, l = j >> 8, jj = j & (DH - 1);
        bConvP[j] = b_conv[l * DH + invp(jj)];
      }
    } else {
      int t3 = t2 - B_TOT;
      if (t3 < N_EDGES) atomicAdd(&cnt[edst[t3]], 1);
    }
  }
}

// ---------------- f16 MFMA GEMM: A via LDS, B direct from L2 ----------------
// C[M][N] = A[M][K']·B2[K'][N]; A = (Ahi, Alo) f16 [M][K] (feature order = caller's).
// NSPLIT=1: K'=K. NSPLIT=3: K'=3K, (Ahi·Bhi)+(Ahi·Blo)+(Alo·Bhi); Bt segments
// [0,K) hi, [K,2K) lo, [2K,3K) hi. Bt = B2^T [N][K'] f16 (L2-resident weight).
// BM=128, BK=64, 4 waves, wave tile 64 x (BN/2). A staged via GLD16 in
// fragment-order LDS (conflict-free); B fragments loaded straight to VGPRs.
// EPI 0: Cf fp32 + bias, TRUE col order (scalar stores).
// EPI 1: Cb f16 + biasp, PERM col order (ushort4 stores), row-major [M][N].
// EPI 2: Cb f16 + biasp, PERM col order, SLICE-MAJOR [8][M][32] (32-feature
//        slices contiguous per slice -> XCD-L2-resident gather target).
// EPI 1/2 require BN=128 (NT==4); guarded with if constexpr so other
// instantiations never compile the 4-column epilogue (round-6 fix).
template <int BN, int NSPLIT, int EPI>
__global__ __launch_bounds__(256) void k_gemm_mfma(
    const u16* __restrict__ Ahi, const u16* __restrict__ Alo,
    const u16* __restrict__ Bt, const float* __restrict__ bias,
    float* __restrict__ Cf, u16* __restrict__ Cb, int M, int K, int N) {
  constexpr int BM = 128, BK = 64;
  constexpr int WN = BN / 2;
  constexpr int NT = WN / 16;
  __shared__ u16 As[2 * 8 * 512];  // (kb, g<8, lane*8) : 16 KB
  const int tid = threadIdx.x;
  const int w = tid >> 6, lane = tid & 63;
  const int q = lane >> 4, r = lane & 15;
  const int wmg = (w >> 1) * 4;       // A group base for this wave
  const int wn = (w & 1) * WN;
  const int m0 = blockIdx.x * BM, n0 = blockIdx.y * BN;
  const int Kp = NSPLIT * K;
  const int srow = lane & 15;         // staging source row within group
  const int sk = (lane >> 4) * 8;     // staging source k offset

  f32x4 acc[4][NT];
#pragma unroll
  for (int t = 0; t < 4; t++)
#pragma unroll
    for (int u = 0; u < NT; u++) acc[t][u] = (f32x4){0.f, 0.f, 0.f, 0.f};

  for (int k0 = 0; k0 < Kp; k0 += BK) {
    const u16* Aptr;
    int ka;
    if (NSPLIT == 1) {
      Aptr = Ahi; ka = k0;
    } else {
      Aptr = (k0 < 2 * K) ? Ahi : Alo;
      ka = (k0 < K) ? k0 : ((k0 < 2 * K) ? (k0 - K) : (k0 - 2 * K));
    }
    // stage A: 16 slots over 4 waves x 4 issues
#pragma unroll
    for (int ii = 0; ii < 4; ii++) {
      int g = w * 2 + (ii & 1), kb = ii >> 1;
      int grow = m0 + g * 16 + srow;
      if (grow > M - 1) grow = M - 1;
      const u16* gp = Aptr + (size_t)grow * K + ka + kb * 32 + sk;
      GLD16(gp, &As[(kb * 8 + g) * 512] + (size_t)lane * 8);
    }
    __syncthreads();
#pragma unroll
    for (int kb = 0; kb < 2; kb++) {
      half8 af[4], bfr[NT];
#pragma unroll
      for (int u = 0; u < NT; u++)
        bfr[u] = *(const half8*)(Bt + (size_t)(n0 + wn + u * 16 + r) * Kp +
                                 k0 + kb * 32 + q * 8);
#pragma unroll
      for (int t = 0; t < 4; t++)
        af[t] = *(const half8*)&As[((kb * 8 + wmg + t) * 64 + lane) * 8];
#pragma unroll
      for (int t = 0; t < 4; t++)
#pragma unroll
        for (int u = 0; u < NT; u++)
          acc[t][u] = __builtin_amdgcn_mfma_f32_16x16x32_f16(af[t], bfr[u], acc[t][u], 0, 0, 0);
    }
    __syncthreads();
  }

  if constexpr (EPI >= 1) {
    static_assert(NT == 4, "perm epilogue requires BN=128");
    // perm epilogue: lane holds true cols cb+u*16+r -> stored cb + r*4 + u
    int cb = n0 + wn;
    float4 bp = bias ? *(const float4*)(bias + cb + r * 4)
                     : make_float4(0.f, 0.f, 0.f, 0.f);
    int c = cb + r * 4;
    // EPI1: row-major offset = row*N + c. EPI2: slice-major [8][M][32]:
    // offset = (c>>5)*M*32 + row*32 + (c&31)   (ushort4 stays within slice)
    size_t sb2 = (size_t)(c >> 5) * ((size_t)M * 32) + (c & 31);
#pragma unroll
    for (int t = 0; t < 4; t++) {
#pragma unroll
      for (int rg = 0; rg < 4; rg++) {
        int row = m0 + (w >> 1) * 64 + t * 16 + q * 4 + rg;
        if (row < M) {
          ushort4 o;
          o.x = f2h(acc[t][0][rg] + bp.x);
          o.y = f2h(acc[t][1][rg] + bp.y);
          o.z = f2h(acc[t][2][rg] + bp.z);
          o.w = f2h(acc[t][3][rg] + bp.w);
          if constexpr (EPI == 1)
            *(ushort4*)(Cb + (size_t)row * N + c) = o;
          else
            *(ushort4*)(Cb + sb2 + (size_t)row * 32) = o;
        }
      }
    }
  } else {
    float bv[NT];
#pragma unroll
    for (int u = 0; u < NT; u++) bv[u] = bias ? bias[n0 + wn + u * 16 + r] : 0.f;
#pragma unroll
    for (int t = 0; t < 4; t++) {
#pragma unroll
      for (int rg = 0; rg < 4; rg++) {
        int row = m0 + (w >> 1) * 64 + t * 16 + q * 4 + rg;
        if (row < M) {
#pragma unroll
          for (int u = 0; u < NT; u++) {
            int col = n0 + wn + u * 16 + r;
            Cf[(size_t)row * N + col] = acc[t][u][rg] + bv[u];
          }
        }
      }
    }
  }
}

// ---------------- aggregation v6: XCD-sharded + LDS csr prefetch ----------
// h[i] = tanh(b + dinv[i]^2*tmp[i] + sum_e w_e*tmp[src_e]).
// tmph SLICE-MAJOR [8][n][32]; block = 32 nodes x ONE slice claimed from a
// per-slice atomic queue, own-XCD first (XCC_ID via s_getreg; correctness
// never depends on its value). v5 PROVED residency (FETCH 221->56 MB); v5's
// regression was NT csr on the critical chain + divergence. v6: edges of the
// 32-node chunk are CONTIGUOUS in csr -> bulk cooperative NT load into LDS
// (coalesced, independent, latency-overlapped; csr never pollutes L2), then
// the gather loop runs ds_read -> L2-hit gather only. Two-pass CAP=1024
// handles degree-sum tails with block-uniform bounds (all lanes reach
// __syncthreads). Per-feature accumulation ascending j -> numerics identical.
__global__ __launch_bounds__(256) void k_aggregate(
    const u16* __restrict__ tmph,
    const int* __restrict__ rowptr, const int2* __restrict__ csr,
    const float* __restrict__ dinv, const float* __restrict__ bias,
    u16* __restrict__ hi, u16* __restrict__ lo,
    int* __restrict__ workq, int nchunks, int n) {
  __shared__ int sm[2];
  __shared__ int2 eb[AGG_CAP];
  if (threadIdx.x == 0) {
    int xcc;
    asm volatile("s_getreg_b32 %0, hwreg(HW_REG_XCC_ID)" : "=s"(xcc));
    xcc &= 7;
    int sl = 0, got = 0;
#pragma unroll 1
    for (int t = 0; t < 8; t++) {
      int s2 = (xcc + t) & 7;
      int c = atomicAdd(&workq[s2], 1);
      if (c < nchunks) { sl = s2; got = c; break; }
    }
    sm[0] = sl; sm[1] = got;
  }
  __syncthreads();
  const int slice = sm[0];
  const int chunk = sm[1];
  const int lane = threadIdx.x & 63;
  const int wave = threadIdx.x >> 6;
  const int grp = lane >> 3, sub = lane & 7;
  const int node0 = chunk * 32;
  const int i = node0 + wave * 8 + grp;
  const bool act = i < n;
  const int ic = act ? i : (n - 1);
  const int fo = slice * 32 + sub * 4;     // stored (perm) feature offset
  const u16x4* T = (const u16x4*)(tmph + (size_t)slice * ((size_t)N_NODES * 32));
  const int rs = rowptr[node0];
  const int re = rowptr[node0 + 32 > n ? n : node0 + 32];
  float w0 = dinv[ic];
  w0 *= w0;
  float4 bv = *(const float4*)(bias + fo);
  u16x4 t0 = T[(size_t)ic * 8 + sub];
  float ax = bv.x + w0 * h2f(t0[0]);
  float ay = bv.y + w0 * h2f(t0[1]);
  float az = bv.z + w0 * h2f(t0[2]);
  float aw = bv.w + w0 * h2f(t0[3]);
  const int s = act ? rowptr[i] : 0;
  const int e = act ? rowptr[i + 1] : 0;

  for (int base = rs; base < re; base += AGG_CAP) {
    const int cnt = (re - base < AGG_CAP) ? (re - base) : AGG_CAP;
    // cooperative bulk prefetch csr[base, base+cnt) -> LDS (NT, coalesced)
    for (int t = threadIdx.x; t < cnt; t += 256) {
      i32x2 cv = __builtin_nontemporal_load((const i32x2*)csr + base + t);
      eb[t] = make_int2(cv[0], cv[1]);
    }
    __syncthreads();
    int jl = (s > base ? s : base) - base;
    int jh = ((e < base + cnt) ? e : base + cnt) - base;
    int j = jl;
    for (; j + 16 <= jh; j += 16) {
      int2 c[16];
      u16x4 v[16];
#pragma unroll
      for (int u = 0; u < 16; u++) c[u] = eb[j + u];
#pragma unroll
      for (int u = 0; u < 16; u++) v[u] = T[(size_t)c[u].x * 8 + sub];
#pragma unroll
      for (int u = 0; u < 16; u++) {
        float f = __int_as_float(c[u].y);
        ax += f * h2f(v[u][0]);
        ay += f * h2f(v[u][1]);
        az += f * h2f(v[u][2]);
        aw += f * h2f(v[u][3]);
      }
    }
    if (j < jh) {
      int2 c[16];
      float f[16];
      u16x4 v[16];
#pragma unroll
      for (int u = 0; u < 16; u++) {
        int idx = j + u;
        int cl = idx < jh ? idx : jh - 1;
        c[u] = eb[cl];
        f[u] = idx < jh ? __int_as_float(c[u].y) : 0.f;
      }
#pragma unroll
      for (int u = 0; u < 16; u++) v[u] = T[(size_t)c[u].x * 8 + sub];
#pragma unroll
      for (int u = 0; u < 16; u++) {
        ax += f[u] * h2f(v[u][0]);
        ay += f[u] * h2f(v[u][1]);
        az += f[u] * h2f(v[u][2]);
        aw += f[u] * h2f(v[u][3]);
      }
    }
    __syncthreads();  // eb reused next pass
  }

  if (act) {
    float ox = tanhf(ax), oy = tanhf(ay), oz = tanhf(az), ow = tanhf(aw);
    size_t base = (size_t)i * DH + fo;   // h stays row-major for the GEMMs
    u16x4 hv;
    hv[0] = f2h(ox); hv[1] = f2h(oy); hv[2] = f2h(oz); hv[3] = f2h(ow);
    __builtin_nontemporal_store(hv, (u16x4*)(hi + base));
    if (lo) {
      u16x4 lv;
      lv[0] = f2h(ox - h2f(hv[0]));
      lv[1] = f2h(oy - h2f(hv[1]));
      lv[2] = f2h(oz - h2f(hv[2]));
      lv[3] = f2h(ow - h2f(hv[3]));
      __builtin_nontemporal_store(lv, (u16x4*)(lo + base));
    }
  }
}

// ---------------- launch ----------------

extern "C" void kernel_launch(void* const* d_in, const int* in_sizes, int n_in,
                              void* d_out, int out_size, void* d_ws, size_t ws_size,
                              hipStream_t stream) {
  const float* x = (const float*)d_in[0];
  const int* eidx = (const int*)d_in[1];
  const int* esrc = eidx;
  const int* edst = eidx + N_EDGES;
  const float* W_emb = (const float*)d_in[2];
  const float* b_emb = (const float*)d_in[3];
  const float* W_conv = (const float*)d_in[4];
  const float* b_conv = (const float*)d_in[5];
  const float* W_out = (const float*)d_in[6];
  const float* b_out = (const float*)d_in[7];
  float* out = (float*)d_out;

  char* ws = (char*)d_ws;
  size_t off = 0;
  auto alloc = [&](size_t bytes) -> void* {
    void* p = ws + off;
    off += (bytes + 255) & ~(size_t)255;
    return p;
  };
  u16* tmph = (u16*)alloc((size_t)N_NODES * DH * 2);
  u16* h_hi = (u16*)alloc((size_t)N_NODES * DH * 2);
  u16* h_lo = (u16*)alloc((size_t)N_NODES * DH * 2);
  u16* x_f16 = h_lo;  // alias: x_f16 dead after emb GEMM; h_lo first written at layer-3 agg
  float* dinv = (float*)alloc((size_t)N_NODES * 4);
  int* cnt = (int*)alloc((size_t)N_NODES * 4);
  int* rowptr = (int*)alloc((size_t)(N_NODES + 1) * 4);
  int* cursor = (int*)alloc((size_t)N_NODES * 4);
  int* bsum = (int*)alloc((size_t)((N_NODES + 255) / 256) * 4);
  int2* csr = (int2*)alloc((size_t)N_EDGES * 8);
  u16* Bt_emb = (u16*)alloc((size_t)W_EMB_SZ * 2);
  u16* Bt_conv = (u16*)alloc((size_t)4 * W_CONV_SZ * 2);
  u16* Bt_out = (u16*)alloc((size_t)W_OUT_SZ * 2);
  float* bEmbP = (float*)alloc((size_t)DH * 4);
  float* bConvP = (float*)alloc((size_t)4 * DH * 4);
  int* workq = (int*)alloc((size_t)NLAYERS * 8 * 4);

  int nb = (N_NODES + 255) / 256;
  int eb2 = (N_EDGES + 255) / 256;

  (void)hipMemsetAsync(cnt, 0, (size_t)N_NODES * 4, stream);
  (void)hipMemsetAsync(workq, 0, (size_t)NLAYERS * 8 * 4, stream);
  {
    int tot = X_Q + W_TOT + B_TOT + N_EDGES;
    k_convert<<<(tot + 255) / 256, 256, 0, stream>>>(x, x_f16, W_emb, W_conv, W_out,
                                                     b_emb, b_conv, Bt_emb, Bt_conv,
                                                     Bt_out, bEmbP, bConvP, edst, cnt);
  }
  k_scan1<<<nb, 256, 0, stream>>>(cnt, rowptr, bsum, dinv, N_NODES);
  k_scan2<<<1, 256, 0, stream>>>(bsum, nb);
  k_scan3<<<nb, 256, 0, stream>>>(rowptr, bsum, cursor, N_NODES);
  k_fill<<<eb2, 256, 0, stream>>>(esrc, edst, dinv, cursor, csr, N_EDGES);

  int mblocks = (N_NODES + 127) / 128;  // 391
  int nchunks = (N_NODES + 31) / 32;    // 1563
  int aggblocks = nchunks * 8;          // one block per (chunk, slice)

  // emb: h0 = x @ W_emb + b_emb  -> f16 h_hi (perm cols, row-major)
  {
    dim3 g(mblocks, DH / 128);
    k_gemm_mfma<128, 1, 1><<<g, 256, 0, stream>>>(x_f16, nullptr, Bt_emb, bEmbP,
                                                  nullptr, h_hi, N_NODES, DIN, DH);
  }
  // conv layers: GEMM writes tmph SLICE-MAJOR (EPI 2); layer 3 agg also emits
  // h_lo for the final split GEMM
  for (int l = 0; l < NLAYERS; l++) {
    dim3 g(mblocks, DH / 128);
    k_gemm_mfma<128, 1, 2><<<g, 256, 0, stream>>>(h_hi, nullptr,
                                                  Bt_conv + (size_t)l * W_CONV_SZ, nullptr,
                                                  nullptr, tmph, N_NODES, DH, DH);
    k_aggregate<<<aggblocks, 256, 0, stream>>>(tmph, rowptr, csr, dinv,
                                               bConvP + (size_t)l * DH,
                                               h_hi, (l == 3) ? h_lo : nullptr,
                                               workq + l * 8, nchunks, N_NODES);
  }
  // out = h4 @ W_out + b_out (split-3, fp32 out, TRUE col order)
  {
    dim3 g(mblocks, 1);
    k_gemm_mfma<64, 3, 0><<<g, 256, 0, stream>>>(h_hi, h_lo, Bt_out, b_out,
                                                 out, nullptr, N_NODES, DH, DOUT);
  }
}

// Round 10
// 772.139 us; speedup vs baseline: 1.2982x; 1.2734x over previous
//
#include <hip/hip_runtime.h>
#include <math.h>

#define N_NODES 50000
#define N_EDGES 800000
#define DIN 128
#define DH 256
#define DOUT 64
#define NLAYERS 4
#define AGG_CAP 1024   // LDS edge-buffer entries per chunk (avg block load ~544)
#define AGG_BLOCKS 1536  // persistent blocks (6/CU)

typedef unsigned short u16;
typedef __attribute__((ext_vector_type(8))) _Float16 half8;
typedef __attribute__((ext_vector_type(4))) float f32x4;
typedef __attribute__((ext_vector_type(2))) int i32x2;
typedef __attribute__((ext_vector_type(4))) unsigned short u16x4;

__device__ inline u16 f2h(float f) {
  _Float16 h = (_Float16)f;
  return *(u16*)&h;
}
__device__ inline float h2f(u16 u) {
  _Float16 h = *(_Float16*)&u;
  return (float)h;
}
// stored index j -> true feature index (perm: true c -> (c%16)*4 + c/16 per 64-seg)
__device__ inline int invp(int j) {
  int s = j >> 6, t = j & 63;
  return s * 64 + (t & 3) * 16 + (t >> 2);
}

#define GLD16(gp, lp)                                                        \
  __builtin_amdgcn_global_load_lds(                                          \
      (const __attribute__((address_space(1))) void*)(const void*)(gp),      \
      (__attribute__((address_space(3))) void*)(void*)(lp), 16, 0, 0)

// ---------------- preprocessing ----------------

// scan1 + dinv fused
__global__ void k_scan1(const int* __restrict__ cnt, int* __restrict__ rowptr,
                        int* __restrict__ bsum, float* __restrict__ dinv, int n) {
  __shared__ int sm[256];
  int i = blockIdx.x * 256 + threadIdx.x;
  int v = (i < n) ? cnt[i] : 0;
  if (i < n) dinv[i] = rsqrtf((float)v + 1.0f);  // +1 = self-loop
  sm[threadIdx.x] = v;
  __syncthreads();
  for (int off = 1; off < 256; off <<= 1) {
    int t = (threadIdx.x >= off) ? sm[threadIdx.x - off] : 0;
    __syncthreads();
    sm[threadIdx.x] += t;
    __syncthreads();
  }
  if (i < n) rowptr[i + 1] = sm[threadIdx.x];
  if (threadIdx.x == 255) bsum[blockIdx.x] = sm[255];
}

__global__ void k_scan2(int* bsum, int nb) {
  __shared__ int sm[256];
  int v = (threadIdx.x < nb) ? bsum[threadIdx.x] : 0;
  sm[threadIdx.x] = v;
  __syncthreads();
  for (int off = 1; off < 256; off <<= 1) {
    int t = (threadIdx.x >= off) ? sm[threadIdx.x - off] : 0;
    __syncthreads();
    sm[threadIdx.x] += t;
    __syncthreads();
  }
  if (threadIdx.x < nb) bsum[threadIdx.x] = sm[threadIdx.x] - v;
}

// scan3 + cursor init fused
__global__ void k_scan3(int* __restrict__ rowptr, const int* __restrict__ bsum,
                        int* __restrict__ cursor, int n) {
  int i = blockIdx.x * 256 + threadIdx.x;
  if (i < n) {
    int v = rowptr[i + 1] + bsum[blockIdx.x];
    rowptr[i + 1] = v;
    if (i + 1 < n) cursor[i + 1] = v;
  }
  if (blockIdx.x == 0 && threadIdx.x == 0) {
    rowptr[0] = 0;
    cursor[0] = 0;
  }
}

__global__ void k_fill(const int* __restrict__ src, const int* __restrict__ dst,
                       const float* __restrict__ dinv,
                       int* __restrict__ cursor, int2* __restrict__ csr, int e) {
  int i = blockIdx.x * blockDim.x + threadIdx.x;
  if (i < e) {
    int d = dst[i], s = src[i];
    int pos = atomicAdd(&cursor[d], 1);
    csr[pos] = make_int2(s, __float_as_int(dinv[s] * dinv[d]));
  }
}

// ---------------- convert: x, weights (k-inverse-perm), biases (perm), + count ----
#define X_Q (N_NODES * DIN / 4)        // 1,600,000 float4 groups
#define W_EMB_SZ (DIN * DH)            // 32768 (plain: emb k-dim is unpermuted x)
#define W_CONV_SZ (DH * DH)            // 65536
#define W_OUT_SZ (3 * DH * DOUT)       // 49152
#define W_TOT (W_EMB_SZ + 4 * W_CONV_SZ + W_OUT_SZ)
#define B_TOT (DH + 4 * DH)            // permuted b_emb + b_conv

__global__ void k_convert(const float* __restrict__ x, u16* __restrict__ x_f16,
                          const float* __restrict__ W_emb, const float* __restrict__ W_conv,
                          const float* __restrict__ W_out,
                          const float* __restrict__ b_emb, const float* __restrict__ b_conv,
                          u16* __restrict__ Bt_emb, u16* __restrict__ Bt_conv,
                          u16* __restrict__ Bt_out,
                          float* __restrict__ bEmbP, float* __restrict__ bConvP,
                          const int* __restrict__ edst, int* __restrict__ cnt) {
  int i = blockIdx.x * 256 + threadIdx.x;
  if (i < X_Q) {
    float4 v = ((const float4*)x)[i];
    ushort4 o;
    o.x = f2h(v.x); o.y = f2h(v.y); o.z = f2h(v.z); o.w = f2h(v.w);
    ((ushort4*)x_f16)[i] = o;
    return;
  }
  int t = i - X_Q;
  if (t < W_EMB_SZ) {
    int n = t >> 7, k = t & (DIN - 1);           // Bt_emb[n][k], k plain
    Bt_emb[t] = f2h(W_emb[k * DH + n]);
  } else if (t < W_EMB_SZ + 4 * W_CONV_SZ) {
    int j = t - W_EMB_SZ;
    int l = j >> 16, jj = j & (W_CONV_SZ - 1);
    int n = jj >> 8, k2 = jj & (DH - 1);         // Bt_conv[n][k2], k2 = perm space
    Bt_conv[j] = f2h(W_conv[l * W_CONV_SZ + invp(k2) * DH + n]);
  } else if (t < W_TOT) {
    int j = t - W_EMB_SZ - 4 * W_CONV_SZ;
    int n = j / (3 * DH), kp = j % (3 * DH);     // Bt_out[n][kp]: 0..255 hi,256.. lo,512.. hi
    int s0 = kp >> 8, k2 = kp & (DH - 1);
    float wv = W_out[invp(k2) * DOUT + n];
    u16 hiv = f2h(wv);
    u16 v = hiv;
    if (s0 == 1) v = f2h(wv - h2f(hiv));
    Bt_out[j] = v;
  } else {
    int t2 = t - W_TOT;
    if (t2 < B_TOT) {
      if (t2 < DH) bEmbP[t2] = b_emb[invp(t2)];
      else {
        int j = t2 - DH, l = j >> 8, jj = j & (DH - 1);
        bConvP[j] = b_conv[l * DH + invp(jj)];
      }
    } else {
      int t3 = t2 - B_TOT;
      if (t3 < N_EDGES) atomicAdd(&cnt[edst[t3]], 1);
    }
  }
}

// ---------------- f16 MFMA GEMM: A via LDS, B direct from L2 ----------------
// C[M][N] = A[M][K']·B2[K'][N]; A = (Ahi, Alo) f16 [M][K] (feature order = caller's).
// NSPLIT=1: K'=K. NSPLIT=3: K'=3K, (Ahi·Bhi)+(Ahi·Blo)+(Alo·Bhi); Bt segments
// [0,K) hi, [K,2K) lo, [2K,3K) hi. Bt = B2^T [N][K'] f16 (L2-resident weight).
// BM=128, BK=64, 4 waves, wave tile 64 x (BN/2). A staged via GLD16 in
// fragment-order LDS (conflict-free); B fragments loaded straight to VGPRs.
// EPI 0: Cf fp32 + bias, TRUE col order (scalar stores).
// EPI 1: Cb f16 + biasp, PERM col order (ushort4 stores), row-major [M][N].
// EPI 2: Cb f16 + biasp, PERM col order, SLICE-MAJOR [8][M][32] (32-feature
//        slices contiguous per slice -> XCD-L2-resident gather target).
// EPI 1/2 require BN=128 (NT==4); if constexpr-guarded (round-6 fix).
template <int BN, int NSPLIT, int EPI>
__global__ __launch_bounds__(256) void k_gemm_mfma(
    const u16* __restrict__ Ahi, const u16* __restrict__ Alo,
    const u16* __restrict__ Bt, const float* __restrict__ bias,
    float* __restrict__ Cf, u16* __restrict__ Cb, int M, int K, int N) {
  constexpr int BM = 128, BK = 64;
  constexpr int WN = BN / 2;
  constexpr int NT = WN / 16;
  __shared__ u16 As[2 * 8 * 512];  // (kb, g<8, lane*8) : 16 KB
  const int tid = threadIdx.x;
  const int w = tid >> 6, lane = tid & 63;
  const int q = lane >> 4, r = lane & 15;
  const int wmg = (w >> 1) * 4;       // A group base for this wave
  const int wn = (w & 1) * WN;
  const int m0 = blockIdx.x * BM, n0 = blockIdx.y * BN;
  const int Kp = NSPLIT * K;
  const int srow = lane & 15;         // staging source row within group
  const int sk = (lane >> 4) * 8;     // staging source k offset

  f32x4 acc[4][NT];
#pragma unroll
  for (int t = 0; t < 4; t++)
#pragma unroll
    for (int u = 0; u < NT; u++) acc[t][u] = (f32x4){0.f, 0.f, 0.f, 0.f};

  for (int k0 = 0; k0 < Kp; k0 += BK) {
    const u16* Aptr;
    int ka;
    if (NSPLIT == 1) {
      Aptr = Ahi; ka = k0;
    } else {
      Aptr = (k0 < 2 * K) ? Ahi : Alo;
      ka = (k0 < K) ? k0 : ((k0 < 2 * K) ? (k0 - K) : (k0 - 2 * K));
    }
    // stage A: 16 slots over 4 waves x 4 issues
#pragma unroll
    for (int ii = 0; ii < 4; ii++) {
      int g = w * 2 + (ii & 1), kb = ii >> 1;
      int grow = m0 + g * 16 + srow;
      if (grow > M - 1) grow = M - 1;
      const u16* gp = Aptr + (size_t)grow * K + ka + kb * 32 + sk;
      GLD16(gp, &As[(kb * 8 + g) * 512] + (size_t)lane * 8);
    }
    __syncthreads();
#pragma unroll
    for (int kb = 0; kb < 2; kb++) {
      half8 af[4], bfr[NT];
#pragma unroll
      for (int u = 0; u < NT; u++)
        bfr[u] = *(const half8*)(Bt + (size_t)(n0 + wn + u * 16 + r) * Kp +
                                 k0 + kb * 32 + q * 8);
#pragma unroll
      for (int t = 0; t < 4; t++)
        af[t] = *(const half8*)&As[((kb * 8 + wmg + t) * 64 + lane) * 8];
#pragma unroll
      for (int t = 0; t < 4; t++)
#pragma unroll
        for (int u = 0; u < NT; u++)
          acc[t][u] = __builtin_amdgcn_mfma_f32_16x16x32_f16(af[t], bfr[u], acc[t][u], 0, 0, 0);
    }
    __syncthreads();
  }

  if constexpr (EPI >= 1) {
    static_assert(NT == 4, "perm epilogue requires BN=128");
    // perm epilogue: lane holds true cols cb+u*16+r -> stored cb + r*4 + u
    int cb = n0 + wn;
    float4 bp = bias ? *(const float4*)(bias + cb + r * 4)
                     : make_float4(0.f, 0.f, 0.f, 0.f);
    int c = cb + r * 4;
    // EPI1: row-major offset = row*N + c. EPI2: slice-major [8][M][32]:
    // offset = (c>>5)*M*32 + row*32 + (c&31)   (ushort4 stays within slice)
    size_t sb2 = (size_t)(c >> 5) * ((size_t)M * 32) + (c & 31);
#pragma unroll
    for (int t = 0; t < 4; t++) {
#pragma unroll
      for (int rg = 0; rg < 4; rg++) {
        int row = m0 + (w >> 1) * 64 + t * 16 + q * 4 + rg;
        if (row < M) {
          ushort4 o;
          o.x = f2h(acc[t][0][rg] + bp.x);
          o.y = f2h(acc[t][1][rg] + bp.y);
          o.z = f2h(acc[t][2][rg] + bp.z);
          o.w = f2h(acc[t][3][rg] + bp.w);
          if constexpr (EPI == 1)
            *(ushort4*)(Cb + (size_t)row * N + c) = o;
          else
            *(ushort4*)(Cb + sb2 + (size_t)row * 32) = o;
        }
      }
    }
  } else {
    float bv[NT];
#pragma unroll
    for (int u = 0; u < NT; u++) bv[u] = bias ? bias[n0 + wn + u * 16 + r] : 0.f;
#pragma unroll
    for (int t = 0; t < 4; t++) {
#pragma unroll
      for (int rg = 0; rg < 4; rg++) {
        int row = m0 + (w >> 1) * 64 + t * 16 + q * 4 + rg;
        if (row < M) {
#pragma unroll
          for (int u = 0; u < NT; u++) {
            int col = n0 + wn + u * 16 + r;
            Cf[(size_t)row * N + col] = acc[t][u][rg] + bv[u];
          }
        }
      }
    }
  }
}

// ---------------- aggregation v7: persistent XCD-sharded + pipelined prefetch --
// h[i] = tanh(b + dinv[i]^2*tmp[i] + sum_e w_e*tmp[src_e]).
// tmph SLICE-MAJOR [8][n][32]. v6 proved residency (FETCH 221->40 MB) but per-
// block overheads (claim atomic + serial csr prefetch + barriers x 12504 blocks)
// ate the gain. v7: 1536 PERSISTENT blocks; tid0 claims chunks from per-slice
// padded queues (own XCD first via XCC_ID; correctness never depends on it) and
// publishes via parity-double-buffered sm slots; csr prefetch double-buffered in
// LDS with ONE barrier per chunk -- claim + prefetch latency hide under the
// previous chunk's gather. No inter-block waiting anywhere: a block that finds
// all queues drained exits immediately (no deadlock under any scheduling).
// Overflow (>1024 edges/chunk; never at these degree stats) reads csr
// direct-global, ascending. Per-(node,feature) accumulation order (ascending j,
// 16-chunks + clamped-16 tail) identical to prior rounds.
__global__ __launch_bounds__(256) void k_aggregate(
    const u16* __restrict__ tmph,
    const int* __restrict__ rowptr, const int2* __restrict__ csr,
    const float* __restrict__ dinv, const float* __restrict__ bias,
    u16* __restrict__ hi, u16* __restrict__ lo,
    int* __restrict__ workq, int nchunks, int n) {
  __shared__ int smS[2], smC[2];
  __shared__ int2 eb[2][AGG_CAP];
  const int tid = threadIdx.x;
  const int lane = tid & 63;
  const int wave = tid >> 6;
  const int grp = lane >> 3, sub = lane & 7;

  int scur, tries;
  if (tid == 0) {
    int xcc;
    asm volatile("s_getreg_b32 %0, hwreg(HW_REG_XCC_ID)" : "=s"(xcc));
    scur = xcc & 7;
    tries = 0;
    int sl = -1, ch = -1;
#pragma unroll 1
    while (tries < 8) {
      int c = atomicAdd(&workq[scur * 16], 1);
      if (c < nchunks) { sl = scur; ch = c; break; }
      scur = (scur + 1) & 7;
      tries++;
    }
    smS[0] = sl; smC[0] = ch;
  }
  __syncthreads();
  int cs = smS[0], cc = smC[0];
  if (cs < 0) return;

  // prologue prefetch chunk (cs,cc) -> eb[0]
  {
    int node0 = cc * 32;
    int hi2 = node0 + 32 > n ? n : node0 + 32;
    int rs = rowptr[node0], re = rowptr[hi2];
    int cnt = re - rs < AGG_CAP ? re - rs : AGG_CAP;
    for (int t = tid; t < cnt; t += 256) {
      i32x2 cv = __builtin_nontemporal_load((const i32x2*)csr + rs + t);
      eb[0][t] = make_int2(cv[0], cv[1]);
    }
  }

  int it = 0;
#pragma unroll 1
  while (true) {
    // claim next chunk (tid0, before barrier -> latency hidden)
    if (tid == 0) {
      int sl = -1, ch = -1;
#pragma unroll 1
      while (tries < 8) {
        int c = atomicAdd(&workq[scur * 16], 1);
        if (c < nchunks) { sl = scur; ch = c; break; }
        scur = (scur + 1) & 7;
        tries++;
      }
      smS[(it + 1) & 1] = sl; smC[(it + 1) & 1] = ch;
    }
    __syncthreads();  // eb[it&1] prefetch complete; next-claim slot visible
    const int ns = smS[(it + 1) & 1], nc = smC[(it + 1) & 1];

    // current chunk geometry
    const int node0 = cc * 32;
    const int hi2 = node0 + 32 > n ? n : node0 + 32;
    const int rs = rowptr[node0];
    const int re = rowptr[hi2];
    const int cnt = re - rs < AGG_CAP ? re - rs : AGG_CAP;

    // issue prefetch for next chunk into eb[(it+1)&1] (overlaps gather below)
    if (ns >= 0) {
      int nn0 = nc * 32;
      int nhi = nn0 + 32 > n ? n : nn0 + 32;
      int nrs = rowptr[nn0], nre = rowptr[nhi];
      int ncnt = nre - nrs < AGG_CAP ? nre - nrs : AGG_CAP;
      for (int t = tid; t < ncnt; t += 256) {
        i32x2 cv = __builtin_nontemporal_load((const i32x2*)csr + nrs + t);
        eb[(it + 1) & 1][t] = make_int2(cv[0], cv[1]);
      }
    }

    // gather current chunk from eb[it&1]
    {
      const int2* ebp = eb[it & 1];
      const int i = node0 + wave * 8 + grp;
      const bool act = i < n;
      const int ic = act ? i : (n - 1);
      const int fo = cs * 32 + sub * 4;
      const u16x4* T = (const u16x4*)(tmph + (size_t)cs * ((size_t)N_NODES * 32));
      float w0 = dinv[ic];
      w0 *= w0;
      float4 bv = *(const float4*)(bias + fo);
      u16x4 t0 = T[(size_t)ic * 8 + sub];
      float ax = bv.x + w0 * h2f(t0[0]);
      float ay = bv.y + w0 * h2f(t0[1]);
      float az = bv.z + w0 * h2f(t0[2]);
      float aw = bv.w + w0 * h2f(t0[3]);
      const int s = act ? rowptr[i] : 0;
      const int e = act ? rowptr[i + 1] : 0;
      int jl = (s - rs) > 0 ? (s - rs) : 0;
      int eL = e < rs + cnt ? e : rs + cnt;  // LDS-covered end (global idx)
      int jh = eL - rs;
      int j = jl;
      for (; j + 16 <= jh; j += 16) {
        int2 c[16];
        u16x4 v[16];
#pragma unroll
        for (int u = 0; u < 16; u++) c[u] = ebp[j + u];
#pragma unroll
        for (int u = 0; u < 16; u++) v[u] = T[(size_t)c[u].x * 8 + sub];
#pragma unroll
        for (int u = 0; u < 16; u++) {
          float f = __int_as_float(c[u].y);
          ax += f * h2f(v[u][0]);
          ay += f * h2f(v[u][1]);
          az += f * h2f(v[u][2]);
          aw += f * h2f(v[u][3]);
        }
      }
      if (j < jh) {
        int2 c[16];
        float f[16];
        u16x4 v[16];
#pragma unroll
        for (int u = 0; u < 16; u++) {
          int idx = j + u;
          int cl = idx < jh ? idx : jh - 1;
          c[u] = ebp[cl];
          f[u] = idx < jh ? __int_as_float(c[u].y) : 0.f;
        }
#pragma unroll
        for (int u = 0; u < 16; u++) v[u] = T[(size_t)c[u].x * 8 + sub];
#pragma unroll
        for (int u = 0; u < 16; u++) {
          ax += f[u] * h2f(v[u][0]);
          ay += f[u] * h2f(v[u][1]);
          az += f[u] * h2f(v[u][2]);
          aw += f[u] * h2f(v[u][3]);
        }
      }
      // overflow tail (chunk edges beyond LDS cap; never at these stats)
      for (int g = eL; g < e; g++) {
        int2 c = csr[g];
        u16x4 v = T[(size_t)c.x * 8 + sub];
        float f = __int_as_float(c.y);
        ax += f * h2f(v[0]);
        ay += f * h2f(v[1]);
        az += f * h2f(v[2]);
        aw += f * h2f(v[3]);
      }
      if (act) {
        float ox = tanhf(ax), oy = tanhf(ay), oz = tanhf(az), ow = tanhf(aw);
        size_t base = (size_t)i * DH + fo;  // h stays row-major for the GEMMs
        u16x4 hv;
        hv[0] = f2h(ox); hv[1] = f2h(oy); hv[2] = f2h(oz); hv[3] = f2h(ow);
        __builtin_nontemporal_store(hv, (u16x4*)(hi + base));
        if (lo) {
          u16x4 lv;
          lv[0] = f2h(ox - h2f(hv[0]));
          lv[1] = f2h(oy - h2f(hv[1]));
          lv[2] = f2h(oz - h2f(hv[2]));
          lv[3] = f2h(ow - h2f(hv[3]));
          __builtin_nontemporal_store(lv, (u16x4*)(lo + base));
        }
      }
    }

    cs = ns; cc = nc; it++;
    if (cs < 0) break;
  }
}

// ---------------- launch ----------------

extern "C" void kernel_launch(void* const* d_in, const int* in_sizes, int n_in,
                              void* d_out, int out_size, void* d_ws, size_t ws_size,
                              hipStream_t stream) {
  const float* x = (const float*)d_in[0];
  const int* eidx = (const int*)d_in[1];
  const int* esrc = eidx;
  const int* edst = eidx + N_EDGES;
  const float* W_emb = (const float*)d_in[2];
  const float* b_emb = (const float*)d_in[3];
  const float* W_conv = (const float*)d_in[4];
  const float* b_conv = (const float*)d_in[5];
  const float* W_out = (const float*)d_in[6];
  const float* b_out = (const float*)d_in[7];
  float* out = (float*)d_out;

  char* ws = (char*)d_ws;
  size_t off = 0;
  auto alloc = [&](size_t bytes) -> void* {
    void* p = ws + off;
    off += (bytes + 255) & ~(size_t)255;
    return p;
  };
  u16* tmph = (u16*)alloc((size_t)N_NODES * DH * 2);
  u16* h_hi = (u16*)alloc((size_t)N_NODES * DH * 2);
  u16* h_lo = (u16*)alloc((size_t)N_NODES * DH * 2);
  u16* x_f16 = h_lo;  // alias: x_f16 dead after emb GEMM; h_lo first written at layer-3 agg
  float* dinv = (float*)alloc((size_t)N_NODES * 4);
  int* cnt = (int*)alloc((size_t)N_NODES * 4);
  int* rowptr = (int*)alloc((size_t)(N_NODES + 1) * 4);
  int* cursor = (int*)alloc((size_t)N_NODES * 4);
  int* bsum = (int*)alloc((size_t)((N_NODES + 255) / 256) * 4);
  int2* csr = (int2*)alloc((size_t)N_EDGES * 8);
  u16* Bt_emb = (u16*)alloc((size_t)W_EMB_SZ * 2);
  u16* Bt_conv = (u16*)alloc((size_t)4 * W_CONV_SZ * 2);
  u16* Bt_out = (u16*)alloc((size_t)W_OUT_SZ * 2);
  float* bEmbP = (float*)alloc((size_t)DH * 4);
  float* bConvP = (float*)alloc((size_t)4 * DH * 4);
  int* workq = (int*)alloc((size_t)NLAYERS * 8 * 16 * 4);  // padded: 1 line per slice

  int nb = (N_NODES + 255) / 256;
  int eb2 = (N_EDGES + 255) / 256;

  (void)hipMemsetAsync(cnt, 0, (size_t)N_NODES * 4, stream);
  (void)hipMemsetAsync(workq, 0, (size_t)NLAYERS * 8 * 16 * 4, stream);
  {
    int tot = X_Q + W_TOT + B_TOT + N_EDGES;
    k_convert<<<(tot + 255) / 256, 256, 0, stream>>>(x, x_f16, W_emb, W_conv, W_out,
                                                     b_emb, b_conv, Bt_emb, Bt_conv,
                                                     Bt_out, bEmbP, bConvP, edst, cnt);
  }
  k_scan1<<<nb, 256, 0, stream>>>(cnt, rowptr, bsum, dinv, N_NODES);
  k_scan2<<<1, 256, 0, stream>>>(bsum, nb);
  k_scan3<<<nb, 256, 0, stream>>>(rowptr, bsum, cursor, N_NODES);
  k_fill<<<eb2, 256, 0, stream>>>(esrc, edst, dinv, cursor, csr, N_EDGES);

  int mblocks = (N_NODES + 127) / 128;  // 391
  int nchunks = (N_NODES + 31) / 32;    // 1563

  // emb: h0 = x @ W_emb + b_emb  -> f16 h_hi (perm cols, row-major)
  {
    dim3 g(mblocks, DH / 128);
    k_gemm_mfma<128, 1, 1><<<g, 256, 0, stream>>>(x_f16, nullptr, Bt_emb, bEmbP,
                                                  nullptr, h_hi, N_NODES, DIN, DH);
  }
  // conv layers: GEMM writes tmph SLICE-MAJOR (EPI 2); layer 3 agg also emits
  // h_lo for the final split GEMM
  for (int l = 0; l < NLAYERS; l++) {
    dim3 g(mblocks, DH / 128);
    k_gemm_mfma<128, 1, 2><<<g, 256, 0, stream>>>(h_hi, nullptr,
                                                  Bt_conv + (size_t)l * W_CONV_SZ, nullptr,
                                                  nullptr, tmph, N_NODES, DH, DH);
    k_aggregate<<<AGG_BLOCKS, 256, 0, stream>>>(tmph, rowptr, csr, dinv,
                                                bConvP + (size_t)l * DH,
                                                h_hi, (l == 3) ? h_lo : nullptr,
                                                workq + l * 8 * 16, nchunks, N_NODES);
  }
  // out = h4 @ W_out + b_out (split-3, fp32 out, TRUE col order)
  {
    dim3 g(mblocks, 1);
    k_gemm_mfma<64, 3, 0><<<g, 256, 0, stream>>>(h_hi, h_lo, Bt_out, b_out,
                                                 out, nullptr, N_NODES, DH, DOUT);
  }
}

// Round 11
// 546.354 us; speedup vs baseline: 1.8347x; 1.4133x over previous
//
#include <hip/hip_runtime.h>
#include <math.h>

#define N_NODES 50000
#define N_EDGES 800000
#define DIN 128
#define DH 256
#define DOUT 64
#define NLAYERS 4

typedef unsigned short u16;
typedef __attribute__((ext_vector_type(8))) _Float16 half8;
typedef __attribute__((ext_vector_type(4))) float f32x4;
typedef __attribute__((ext_vector_type(4), aligned(8))) int int4a;

__device__ inline u16 f2h(float f) {
  _Float16 h = (_Float16)f;
  return *(u16*)&h;
}
__device__ inline float h2f(u16 u) {
  _Float16 h = *(_Float16*)&u;
  return (float)h;
}
// stored index j -> true feature index (perm: true c -> (c%16)*4 + c/16 per 64-seg)
__device__ inline int invp(int j) {
  int s = j >> 6, t = j & 63;
  return s * 64 + (t & 3) * 16 + (t >> 2);
}

#define GLD16(gp, lp)                                                        \
  __builtin_amdgcn_global_load_lds(                                          \
      (const __attribute__((address_space(1))) void*)(const void*)(gp),      \
      (__attribute__((address_space(3))) void*)(void*)(lp), 16, 0, 0)

// ---------------- preprocessing ----------------

// scan1 + dinv fused
__global__ void k_scan1(const int* __restrict__ cnt, int* __restrict__ rowptr,
                        int* __restrict__ bsum, float* __restrict__ dinv, int n) {
  __shared__ int sm[256];
  int i = blockIdx.x * 256 + threadIdx.x;
  int v = (i < n) ? cnt[i] : 0;
  if (i < n) dinv[i] = rsqrtf((float)v + 1.0f);  // +1 = self-loop
  sm[threadIdx.x] = v;
  __syncthreads();
  for (int off = 1; off < 256; off <<= 1) {
    int t = (threadIdx.x >= off) ? sm[threadIdx.x - off] : 0;
    __syncthreads();
    sm[threadIdx.x] += t;
    __syncthreads();
  }
  if (i < n) rowptr[i + 1] = sm[threadIdx.x];
  if (threadIdx.x == 255) bsum[blockIdx.x] = sm[255];
}

__global__ void k_scan2(int* bsum, int nb) {
  __shared__ int sm[256];
  int v = (threadIdx.x < nb) ? bsum[threadIdx.x] : 0;
  sm[threadIdx.x] = v;
  __syncthreads();
  for (int off = 1; off < 256; off <<= 1) {
    int t = (threadIdx.x >= off) ? sm[threadIdx.x - off] : 0;
    __syncthreads();
    sm[threadIdx.x] += t;
    __syncthreads();
  }
  if (threadIdx.x < nb) bsum[threadIdx.x] = sm[threadIdx.x] - v;
}

// scan3 + cursor init fused
__global__ void k_scan3(int* __restrict__ rowptr, const int* __restrict__ bsum,
                        int* __restrict__ cursor, int n) {
  int i = blockIdx.x * 256 + threadIdx.x;
  if (i < n) {
    int v = rowptr[i + 1] + bsum[blockIdx.x];
    rowptr[i + 1] = v;
    if (i + 1 < n) cursor[i + 1] = v;
  }
  if (blockIdx.x == 0 && threadIdx.x == 0) {
    rowptr[0] = 0;
    cursor[0] = 0;
  }
}

__global__ void k_fill(const int* __restrict__ src, const int* __restrict__ dst,
                       const float* __restrict__ dinv,
                       int* __restrict__ cursor, int2* __restrict__ csr, int e) {
  int i = blockIdx.x * blockDim.x + threadIdx.x;
  if (i < e) {
    int d = dst[i], s = src[i];
    int pos = atomicAdd(&cursor[d], 1);
    csr[pos] = make_int2(s, __float_as_int(dinv[s] * dinv[d]));
  }
}

// ---------------- convert: x, weights (k-inverse-perm), biases (perm), + count ----
#define X_Q (N_NODES * DIN / 4)        // 1,600,000 float4 groups
#define W_EMB_SZ (DIN * DH)            // 32768 (plain: emb k-dim is unpermuted x)
#define W_CONV_SZ (DH * DH)            // 65536
#define W_OUT_SZ (3 * DH * DOUT)       // 49152
#define W_TOT (W_EMB_SZ + 4 * W_CONV_SZ + W_OUT_SZ)
#define B_TOT (DH + 4 * DH)            // permuted b_emb + b_conv

__global__ void k_convert(const float* __restrict__ x, u16* __restrict__ x_f16,
                          const float* __restrict__ W_emb, const float* __restrict__ W_conv,
                          const float* __restrict__ W_out,
                          const float* __restrict__ b_emb, const float* __restrict__ b_conv,
                          u16* __restrict__ Bt_emb, u16* __restrict__ Bt_conv,
                          u16* __restrict__ Bt_out,
                          float* __restrict__ bEmbP, float* __restrict__ bConvP,
                          const int* __restrict__ edst, int* __restrict__ cnt) {
  int i = blockIdx.x * 256 + threadIdx.x;
  if (i < X_Q) {
    float4 v = ((const float4*)x)[i];
    ushort4 o;
    o.x = f2h(v.x); o.y = f2h(v.y); o.z = f2h(v.z); o.w = f2h(v.w);
    ((ushort4*)x_f16)[i] = o;
    return;
  }
  int t = i - X_Q;
  if (t < W_EMB_SZ) {
    int n = t >> 7, k = t & (DIN - 1);           // Bt_emb[n][k], k plain
    Bt_emb[t] = f2h(W_emb[k * DH + n]);
  } else if (t < W_EMB_SZ + 4 * W_CONV_SZ) {
    int j = t - W_EMB_SZ;
    int l = j >> 16, jj = j & (W_CONV_SZ - 1);
    int n = jj >> 8, k2 = jj & (DH - 1);         // Bt_conv[n][k2], k2 = perm space
    Bt_conv[j] = f2h(W_conv[l * W_CONV_SZ + invp(k2) * DH + n]);
  } else if (t < W_TOT) {
    int j = t - W_EMB_SZ - 4 * W_CONV_SZ;
    int n = j / (3 * DH), kp = j % (3 * DH);     // Bt_out[n][kp]: 0..255 hi,256.. lo,512.. hi
    int s0 = kp >> 8, k2 = kp & (DH - 1);
    float wv = W_out[invp(k2) * DOUT + n];
    u16 hiv = f2h(wv);
    u16 v = hiv;
    if (s0 == 1) v = f2h(wv - h2f(hiv));
    Bt_out[j] = v;
  } else {
    int t2 = t - W_TOT;
    if (t2 < B_TOT) {
      if (t2 < DH) bEmbP[t2] = b_emb[invp(t2)];
      else {
        int j = t2 - DH, l = j >> 8, jj = j & (DH - 1);
        bConvP[j] = b_conv[l * DH + invp(jj)];
      }
    } else {
      int t3 = t2 - B_TOT;
      if (t3 < N_EDGES) atomicAdd(&cnt[edst[t3]], 1);
    }
  }
}

// ---------------- f16 MFMA GEMM: A via LDS, B direct from L2 ----------------
// C[M][N] = A[M][K']·B2[K'][N]; A = (Ahi, Alo) f16 [M][K].
// NSPLIT=1: K'=K. NSPLIT=3: K'=3K, (Ahi·Bhi)+(Ahi·Blo)+(Alo·Bhi).
// Bt = B2^T [N][K'] f16 (L2-resident weight).
// BM=128, BK=64. NTHREADS=256: 4 waves (2M x 2N), wave tile 64 x BN/2.
// NTHREADS=512 (BN=256): 8 waves (2M x 4N), wave tile 64x64 -- ONE A-stage
// per block-row serves all 256 cols (kills the grid-y=2 A-restage of the
// BN=128 config; staging issues per wave halve; per-wave VGPR unchanged).
// A staged via GLD16 in fragment-order LDS (conflict-free); B frags from L2.
// EPI 0: Cf fp32 + bias, TRUE col order (scalar stores).
// EPI 1: Cb f16 + biasp, PERM col order (ushort4 stores); requires wave NT==4.
template <int BN, int NSPLIT, int EPI, int NTHREADS>
__global__ __launch_bounds__(NTHREADS) void k_gemm_mfma(
    const u16* __restrict__ Ahi, const u16* __restrict__ Alo,
    const u16* __restrict__ Bt, const float* __restrict__ bias,
    float* __restrict__ Cf, u16* __restrict__ Cb, int M, int K, int N) {
  constexpr int BM = 128, BK = 64;
  constexpr int WAVES = NTHREADS / 64;
  constexpr int WN = (BN == 256) ? 64 : BN / 2;
  constexpr int NT = WN / 16;
  __shared__ u16 As[2 * 8 * 512];  // (kb, g<8, lane*8) : 16 KB
  const int tid = threadIdx.x;
  const int w = tid >> 6, lane = tid & 63;
  const int q = lane >> 4, r = lane & 15;
  const int wmg = (WAVES == 8) ? (w >> 2) * 4 : (w >> 1) * 4;  // A group base
  const int wn = (WAVES == 8) ? (w & 3) * WN : (w & 1) * WN;
  const int m0 = blockIdx.x * BM, n0 = blockIdx.y * BN;
  const int Kp = NSPLIT * K;
  const int srow = lane & 15;         // staging source row within group
  const int sk = (lane >> 4) * 8;     // staging source k offset

  f32x4 acc[4][NT];
#pragma unroll
  for (int t = 0; t < 4; t++)
#pragma unroll
    for (int u = 0; u < NT; u++) acc[t][u] = (f32x4){0.f, 0.f, 0.f, 0.f};

  for (int k0 = 0; k0 < Kp; k0 += BK) {
    const u16* Aptr;
    int ka;
    if (NSPLIT == 1) {
      Aptr = Ahi; ka = k0;
    } else {
      Aptr = (k0 < 2 * K) ? Ahi : Alo;
      ka = (k0 < K) ? k0 : ((k0 < 2 * K) ? (k0 - K) : (k0 - 2 * K));
    }
    // stage A: 16 slots over WAVES waves
    if constexpr (WAVES == 8) {
#pragma unroll
      for (int ii = 0; ii < 2; ii++) {
        int g = w, kb = ii;
        int grow = m0 + g * 16 + srow;
        if (grow > M - 1) grow = M - 1;
        const u16* gp = Aptr + (size_t)grow * K + ka + kb * 32 + sk;
        GLD16(gp, &As[(kb * 8 + g) * 512] + (size_t)lane * 8);
      }
    } else {
#pragma unroll
      for (int ii = 0; ii < 4; ii++) {
        int g = w * 2 + (ii & 1), kb = ii >> 1;
        int grow = m0 + g * 16 + srow;
        if (grow > M - 1) grow = M - 1;
        const u16* gp = Aptr + (size_t)grow * K + ka + kb * 32 + sk;
        GLD16(gp, &As[(kb * 8 + g) * 512] + (size_t)lane * 8);
      }
    }
    __syncthreads();
#pragma unroll
    for (int kb = 0; kb < 2; kb++) {
      half8 af[4], bfr[NT];
#pragma unroll
      for (int u = 0; u < NT; u++)
        bfr[u] = *(const half8*)(Bt + (size_t)(n0 + wn + u * 16 + r) * Kp +
                                 k0 + kb * 32 + q * 8);
#pragma unroll
      for (int t = 0; t < 4; t++)
        af[t] = *(const half8*)&As[((kb * 8 + wmg + t) * 64 + lane) * 8];
#pragma unroll
      for (int t = 0; t < 4; t++)
#pragma unroll
        for (int u = 0; u < NT; u++)
          acc[t][u] = __builtin_amdgcn_mfma_f32_16x16x32_f16(af[t], bfr[u], acc[t][u], 0, 0, 0);
    }
    __syncthreads();
  }

  const int rowb = m0 + ((WAVES == 8) ? (w >> 2) : (w >> 1)) * 64;
  if constexpr (EPI == 1) {
    static_assert(NT == 4, "perm epilogue requires wave NT==4");
    // perm epilogue: lane holds true cols cb+u*16+r -> stored cb + r*4 + u
    int cb = n0 + wn;
    int c = cb + r * 4;
    float4 bp = bias ? *(const float4*)(bias + c)
                     : make_float4(0.f, 0.f, 0.f, 0.f);
#pragma unroll
    for (int t = 0; t < 4; t++) {
#pragma unroll
      for (int rg = 0; rg < 4; rg++) {
        int row = rowb + t * 16 + q * 4 + rg;
        if (row < M) {
          ushort4 o;
          o.x = f2h(acc[t][0][rg] + bp.x);
          o.y = f2h(acc[t][1][rg] + bp.y);
          o.z = f2h(acc[t][2][rg] + bp.z);
          o.w = f2h(acc[t][3][rg] + bp.w);
          *(ushort4*)(Cb + (size_t)row * N + c) = o;
        }
      }
    }
  } else {
    float bv[NT];
#pragma unroll
    for (int u = 0; u < NT; u++) bv[u] = bias ? bias[n0 + wn + u * 16 + r] : 0.f;
#pragma unroll
    for (int t = 0; t < 4; t++) {
#pragma unroll
      for (int rg = 0; rg < 4; rg++) {
        int row = rowb + t * 16 + q * 4 + rg;
        if (row < M) {
#pragma unroll
          for (int u = 0; u < NT; u++) {
            int col = n0 + wn + u * 16 + r;
            Cf[(size_t)row * N + col] = acc[t][u][rg] + bv[u];
          }
        }
      }
    }
  }
}

// ---------------- aggregation (round-1 form, proven 60.5 us) ----------------
// h[i] = tanh(b + dinv[i]^2*tmp[i] + sum_e w_e*tmp[src_e]); writes f16 hi (+lo).
// Wave-per-node; i wave-uniform (readfirstlane) -> rowptr/dinv/csr on the
// scalar pipe; flat 16-edge chunks (one csr->gather dependency round);
// clamped-16 tail keeps summation order bitwise identical.
__global__ __launch_bounds__(256) void k_aggregate(
    const u16* __restrict__ tmph,
    const int* __restrict__ rowptr, const int2* __restrict__ csr,
    const float* __restrict__ dinv, const float* __restrict__ bias,
    u16* __restrict__ hi, u16* __restrict__ lo, int n) {
  int iw = (int)((blockIdx.x * (size_t)blockDim.x + threadIdx.x) >> 6);
  int i = __builtin_amdgcn_readfirstlane(iw);
  if (i >= n) return;
  int lane = threadIdx.x & 63;
  float w0 = dinv[i];
  w0 *= w0;
  const ushort4* T = (const ushort4*)tmph;
  float4 bv = ((const float4*)bias)[lane];
  int s = rowptr[i], e = rowptr[i + 1];
  ushort4 t0 = T[(size_t)i * 64 + lane];
  float ax = bv.x + w0 * h2f(t0.x);
  float ay = bv.y + w0 * h2f(t0.y);
  float az = bv.z + w0 * h2f(t0.z);
  float aw = bv.w + w0 * h2f(t0.w);
  int j = s;
  // main: full 16-edge chunks, csr pairs via wide uniform loads
  for (; j + 16 <= e; j += 16) {
    int4a q[8];
#pragma unroll
    for (int u = 0; u < 8; u++) q[u] = *(const int4a*)(csr + j + 2 * u);
    ushort4 v[16];
#pragma unroll
    for (int u = 0; u < 8; u++) {
      v[2 * u] = T[(size_t)q[u].x * 64 + lane];
      v[2 * u + 1] = T[(size_t)q[u].z * 64 + lane];
    }
#pragma unroll
    for (int u = 0; u < 8; u++) {
      float f0 = __int_as_float(q[u].y);
      ax += f0 * h2f(v[2 * u].x);
      ay += f0 * h2f(v[2 * u].y);
      az += f0 * h2f(v[2 * u].z);
      aw += f0 * h2f(v[2 * u].w);
      float f1 = __int_as_float(q[u].w);
      ax += f1 * h2f(v[2 * u + 1].x);
      ay += f1 * h2f(v[2 * u + 1].y);
      az += f1 * h2f(v[2 * u + 1].z);
      aw += f1 * h2f(v[2 * u + 1].w);
    }
  }
  // tail: one clamped 16-chunk (<=15 real edges); padded slots add 0.0
  if (j < e) {
    int2 c[16];
    float f[16];
    ushort4 v[16];
#pragma unroll
    for (int u = 0; u < 16; u++) {
      int idx = j + u;
      int cl = idx < e ? idx : e - 1;
      c[u] = csr[cl];
      f[u] = idx < e ? __int_as_float(c[u].y) : 0.f;
    }
#pragma unroll
    for (int u = 0; u < 16; u++) v[u] = T[(size_t)c[u].x * 64 + lane];
#pragma unroll
    for (int u = 0; u < 16; u++) {
      ax += f[u] * h2f(v[u].x);
      ay += f[u] * h2f(v[u].y);
      az += f[u] * h2f(v[u].z);
      aw += f[u] * h2f(v[u].w);
    }
  }
  float ox = tanhf(ax), oy = tanhf(ay), oz = tanhf(az), ow = tanhf(aw);
  size_t base = (size_t)i * DH + lane * 4;
  ushort4 hv;
  hv.x = f2h(ox); hv.y = f2h(oy); hv.z = f2h(oz); hv.w = f2h(ow);
  *(ushort4*)(hi + base) = hv;
  if (lo) {
    ushort4 lv;
    lv.x = f2h(ox - h2f(hv.x));
    lv.y = f2h(oy - h2f(hv.y));
    lv.z = f2h(oz - h2f(hv.z));
    lv.w = f2h(ow - h2f(hv.w));
    *(ushort4*)(lo + base) = lv;
  }
}

// ---------------- launch ----------------

extern "C" void kernel_launch(void* const* d_in, const int* in_sizes, int n_in,
                              void* d_out, int out_size, void* d_ws, size_t ws_size,
                              hipStream_t stream) {
  const float* x = (const float*)d_in[0];
  const int* eidx = (const int*)d_in[1];
  const int* esrc = eidx;
  const int* edst = eidx + N_EDGES;
  const float* W_emb = (const float*)d_in[2];
  const float* b_emb = (const float*)d_in[3];
  const float* W_conv = (const float*)d_in[4];
  const float* b_conv = (const float*)d_in[5];
  const float* W_out = (const float*)d_in[6];
  const float* b_out = (const float*)d_in[7];
  float* out = (float*)d_out;

  char* ws = (char*)d_ws;
  size_t off = 0;
  auto alloc = [&](size_t bytes) -> void* {
    void* p = ws + off;
    off += (bytes + 255) & ~(size_t)255;
    return p;
  };
  u16* tmph = (u16*)alloc((size_t)N_NODES * DH * 2);
  u16* h_hi = (u16*)alloc((size_t)N_NODES * DH * 2);
  u16* h_lo = (u16*)alloc((size_t)N_NODES * DH * 2);
  u16* x_f16 = h_lo;  // alias: x_f16 dead after emb GEMM; h_lo first written at layer-3 agg
  float* dinv = (float*)alloc((size_t)N_NODES * 4);
  int* cnt = (int*)alloc((size_t)N_NODES * 4);
  int* rowptr = (int*)alloc((size_t)(N_NODES + 1) * 4);
  int* cursor = (int*)alloc((size_t)N_NODES * 4);
  int* bsum = (int*)alloc((size_t)((N_NODES + 255) / 256) * 4);
  int2* csr = (int2*)alloc((size_t)N_EDGES * 8);
  u16* Bt_emb = (u16*)alloc((size_t)W_EMB_SZ * 2);
  u16* Bt_conv = (u16*)alloc((size_t)4 * W_CONV_SZ * 2);
  u16* Bt_out = (u16*)alloc((size_t)W_OUT_SZ * 2);
  float* bEmbP = (float*)alloc((size_t)DH * 4);
  float* bConvP = (float*)alloc((size_t)4 * DH * 4);

  int nb = (N_NODES + 255) / 256;
  int eb = (N_EDGES + 255) / 256;

  (void)hipMemsetAsync(cnt, 0, (size_t)N_NODES * 4, stream);
  {
    int tot = X_Q + W_TOT + B_TOT + N_EDGES;
    k_convert<<<(tot + 255) / 256, 256, 0, stream>>>(x, x_f16, W_emb, W_conv, W_out,
                                                     b_emb, b_conv, Bt_emb, Bt_conv,
                                                     Bt_out, bEmbP, bConvP, edst, cnt);
  }
  k_scan1<<<nb, 256, 0, stream>>>(cnt, rowptr, bsum, dinv, N_NODES);
  k_scan2<<<1, 256, 0, stream>>>(bsum, nb);
  k_scan3<<<nb, 256, 0, stream>>>(rowptr, bsum, cursor, N_NODES);
  k_fill<<<eb, 256, 0, stream>>>(esrc, edst, dinv, cursor, csr, N_EDGES);

  int mblocks = (N_NODES + 127) / 128;  // 391
  int aggblocks = (N_NODES * 64 + 255) / 256;

  // emb: h0 = x @ W_emb + b_emb -> f16 h_hi (perm cols); BN=256, one A-stage
  k_gemm_mfma<256, 1, 1, 512><<<mblocks, 512, 0, stream>>>(
      x_f16, nullptr, Bt_emb, bEmbP, nullptr, h_hi, N_NODES, DIN, DH);
  // conv layers: BN=256 single-A-stage GEMM -> tmph (row-major, perm cols);
  // layer 3 agg also emits h_lo for the final split GEMM
  for (int l = 0; l < NLAYERS; l++) {
    k_gemm_mfma<256, 1, 1, 512><<<mblocks, 512, 0, stream>>>(
        h_hi, nullptr, Bt_conv + (size_t)l * W_CONV_SZ, nullptr,
        nullptr, tmph, N_NODES, DH, DH);
    k_aggregate<<<aggblocks, 256, 0, stream>>>(tmph, rowptr, csr, dinv,
                                               bConvP + (size_t)l * DH,
                                               h_hi, (l == 3) ? h_lo : nullptr, N_NODES);
  }
  // out = h4 @ W_out + b_out (split-3, fp32 out, TRUE col order)
  {
    dim3 g(mblocks, 1);
    k_gemm_mfma<64, 3, 0, 256><<<g, 256, 0, stream>>>(h_hi, h_lo, Bt_out, b_out,
                                                      out, nullptr, N_NODES, DH, DOUT);
  }
}